// Round 1
// baseline (2171.818 us; speedup 1.0000x reference)
//
#include <hip/hip_runtime.h>

// LearnedGCN: out = softmax(relu(se @ te), axis=1) @ x @ W.T + b
// N=16384, RANK=10, F=64 (in=out), all fp32.
//
// Flash-style fusion, fixed softmax base (scores >= 0 via relu, max score
// ~20 so exp() cannot overflow fp32; no online-max rescale needed).
//
// Grid: 256 blocks x 512 threads (8 waves).
//   block b  -> rows [b*64, b*64+64), lane = row-within-block
//   wave w   -> j in [w*2048, (w+1)*2048)  (all 64 lanes share j -> uniform loads)
// Per-thread: u[10] row embed, acc[64] fp32, lsum. LDS combine across waves,
// then fused epilogue agg @ W.T + b.

constexpr int N    = 16384;
constexpr int RANK = 10;
constexpr int F    = 64;
constexpr int WAVES  = 8;
constexpr int JCHUNK = N / WAVES;  // 2048

__global__ __launch_bounds__(WAVES * 64)
void gcn_fused(const float* __restrict__ x,
               const float* __restrict__ se,
               const float* __restrict__ te,
               const float* __restrict__ W,
               const float* __restrict__ bias,
               float* __restrict__ out)
{
    const int lane = threadIdx.x & 63;
    const int wave = threadIdx.x >> 6;
    const int row  = (blockIdx.x << 6) + lane;

    // row embedding
    float u[RANK];
#pragma unroll
    for (int r = 0; r < RANK; ++r) u[r] = se[row * RANK + r];

    float acc[F];
#pragma unroll
    for (int k = 0; k < F; ++k) acc[k] = 0.f;
    float lsum = 0.f;

    const int j0 = wave * JCHUNK;
    for (int j = j0; j < j0 + JCHUNK; j += 4) {
        // load target_embed columns j..j+3 (float4 across j; rows stride N)
        float tvv[RANK][4];
#pragma unroll
        for (int r = 0; r < RANK; ++r) {
            const float4 t = *reinterpret_cast<const float4*>(te + r * N + j);
            tvv[r][0] = t.x; tvv[r][1] = t.y; tvv[r][2] = t.z; tvv[r][3] = t.w;
        }

        float p[4];
#pragma unroll
        for (int q = 0; q < 4; ++q) {
            // rank-10 dot, balanced tree to cut dependent latency
            const float d0 = fmaf(u[0], tvv[0][q], u[1] * tvv[1][q]);
            const float d1 = fmaf(u[2], tvv[2][q], u[3] * tvv[3][q]);
            const float d2 = fmaf(u[4], tvv[4][q], u[5] * tvv[5][q]);
            const float d3 = fmaf(u[6], tvv[6][q], u[7] * tvv[7][q]);
            const float d4 = fmaf(u[8], tvv[8][q], u[9] * tvv[9][q]);
            float sc = (d0 + d1) + (d2 + d3) + d4;
            sc = fmaxf(sc, 0.f);          // relu
            p[q] = __expf(sc);            // fixed-base softmax numerator
            lsum += p[q];
        }

        const float4* xj0 = reinterpret_cast<const float4*>(x + (j + 0) * F);
        const float4* xj1 = reinterpret_cast<const float4*>(x + (j + 1) * F);
        const float4* xj2 = reinterpret_cast<const float4*>(x + (j + 2) * F);
        const float4* xj3 = reinterpret_cast<const float4*>(x + (j + 3) * F);
#pragma unroll
        for (int k4 = 0; k4 < F / 4; ++k4) {
            const float4 a0 = xj0[k4];
            const float4 a1 = xj1[k4];
            const float4 a2 = xj2[k4];
            const float4 a3 = xj3[k4];
            acc[4 * k4 + 0] = fmaf(p[0], a0.x, acc[4 * k4 + 0]);
            acc[4 * k4 + 1] = fmaf(p[0], a0.y, acc[4 * k4 + 1]);
            acc[4 * k4 + 2] = fmaf(p[0], a0.z, acc[4 * k4 + 2]);
            acc[4 * k4 + 3] = fmaf(p[0], a0.w, acc[4 * k4 + 3]);
            acc[4 * k4 + 0] = fmaf(p[1], a1.x, acc[4 * k4 + 0]);
            acc[4 * k4 + 1] = fmaf(p[1], a1.y, acc[4 * k4 + 1]);
            acc[4 * k4 + 2] = fmaf(p[1], a1.z, acc[4 * k4 + 2]);
            acc[4 * k4 + 3] = fmaf(p[1], a1.w, acc[4 * k4 + 3]);
            acc[4 * k4 + 0] = fmaf(p[2], a2.x, acc[4 * k4 + 0]);
            acc[4 * k4 + 1] = fmaf(p[2], a2.y, acc[4 * k4 + 1]);
            acc[4 * k4 + 2] = fmaf(p[2], a2.z, acc[4 * k4 + 2]);
            acc[4 * k4 + 3] = fmaf(p[2], a2.w, acc[4 * k4 + 3]);
            acc[4 * k4 + 0] = fmaf(p[3], a3.x, acc[4 * k4 + 0]);
            acc[4 * k4 + 1] = fmaf(p[3], a3.y, acc[4 * k4 + 1]);
            acc[4 * k4 + 2] = fmaf(p[3], a3.z, acc[4 * k4 + 2]);
            acc[4 * k4 + 3] = fmaf(p[3], a3.w, acc[4 * k4 + 3]);
        }
    }

    // ---- combine partial (acc, lsum) across the 8 waves via LDS ----
    __shared__ float s_acc[64][F + 1];   // +1 pad: conflict-free row access
    __shared__ float s_l[64];

    for (int w = 0; w < WAVES; ++w) {
        if (wave == w) {
            if (w == 0) {
#pragma unroll
                for (int k = 0; k < F; ++k) s_acc[lane][k] = acc[k];
                s_l[lane] = lsum;
            } else {
#pragma unroll
                for (int k = 0; k < F; ++k) s_acc[lane][k] += acc[k];
                s_l[lane] += lsum;
            }
        }
        __syncthreads();
    }

    // ---- epilogue: out[row] = (acc/lsum) @ W.T + b ----
    // 512 threads: thread t -> row r = t>>3, output slice oc = t&7 (8 outputs)
    const int r  = threadIdx.x >> 3;
    const int oc = threadIdx.x & 7;
    const float linv = 1.f / s_l[r];
    float a[F];
#pragma unroll
    for (int c = 0; c < F; ++c) a[c] = s_acc[r][c] * linv;

    const int orow = (blockIdx.x << 6) + r;
#pragma unroll
    for (int kk = 0; kk < 8; ++kk) {
        const int k = oc * 8 + kk;
        float o = bias[k];
        const float4* wr = reinterpret_cast<const float4*>(W + k * F);
#pragma unroll
        for (int c4 = 0; c4 < F / 4; ++c4) {
            const float4 wv = wr[c4];
            o = fmaf(a[4 * c4 + 0], wv.x, o);
            o = fmaf(a[4 * c4 + 1], wv.y, o);
            o = fmaf(a[4 * c4 + 2], wv.z, o);
            o = fmaf(a[4 * c4 + 3], wv.w, o);
        }
        out[orow * F + k] = o;
    }
}

extern "C" void kernel_launch(void* const* d_in, const int* in_sizes, int n_in,
                              void* d_out, int out_size, void* d_ws, size_t ws_size,
                              hipStream_t stream) {
    const float* x  = (const float*)d_in[0];
    const float* se = (const float*)d_in[1];
    const float* te = (const float*)d_in[2];
    const float* W  = (const float*)d_in[3];
    const float* b  = (const float*)d_in[4];
    float* out = (float*)d_out;

    gcn_fused<<<N / 64, WAVES * 64, 0, stream>>>(x, se, te, W, b, out);
}

// Round 3
// 434.362 us; speedup vs baseline: 5.0000x; 5.0000x over previous
//
#include <hip/hip_runtime.h>
#include <hip/hip_bf16.h>

// LearnedGCN: out = softmax(relu(se @ te), axis=1) @ x @ W.T + b
// N=16384, RANK=10, F=64, fp32 in/out.
//
// Restructure vs round 1:
//   out = (P @ Y) / lsum + b   where Y = X @ W.T   (P = exp(relu(se@te)), fixed base)
// Pre-kernel: Y = X@W.T in fp32, emitted bf16 pre-packed in MFMA B-fragment order.
// Main kernel: scores fp32 VALU (rank-10) -> exp -> bf16 A-frag; PV via
// mfma_f32_16x16x32_bf16 (fp32 accum). lsum fp32 per-row. 16 rows/wave,
// 4-way j-split, block = 8 waves (2 row-tiles x 4 splits), LDS combine.
//
// Fragment k-mapping: j = jb + 8*(lane>>4) + slot, used identically for A and B
// -> correct for any HW k-layout (consistent permutation cancels in contraction).

constexpr int N    = 16384;
constexpr int RANK = 10;
constexpr int F    = 64;

typedef float f32x4 __attribute__((ext_vector_type(4)));
typedef short bf16x8 __attribute__((ext_vector_type(8)));

static __device__ __forceinline__ unsigned short f2bf(float f) {
    union { float f; unsigned int u; } a; a.f = f;
    unsigned int u = a.u;
    u += 0x7FFFu + ((u >> 16) & 1u);   // round-to-nearest-even
    return (unsigned short)(u >> 16);
}

// ---------------- pre-kernel: Y = X @ W.T -> bf16 B-fragments ----------------
// yfrag layout (uint4 = 8 bf16 = one lane's B-frag for one K-step, one f-tile):
//   yfrag[(jstep*4 + t)*64 + lane], slot b = Y[jstep*32 + 8*(lane>>4) + b][t*16 + (lane&15)]
__global__ __launch_bounds__(256)
void prep_y(const float* __restrict__ x, const float* __restrict__ W,
            uint4* __restrict__ yfrag)
{
    const int js   = blockIdx.x;          // j-step 0..511
    const int tid  = threadIdx.x;
    const int t    = tid >> 6;            // feature tile 0..3
    const int ld   = tid & 63;            // dest lane
    const int g    = ld >> 4;
    const int n16  = ld & 15;
    const int f    = t * 16 + n16;

    float y[8];
#pragma unroll
    for (int b = 0; b < 8; ++b) y[b] = 0.f;

    const float* wr = W + f * F;
    const float* xb = x + (js * 32 + 8 * g) * F;
#pragma unroll
    for (int k4 = 0; k4 < F / 4; ++k4) {
        const float4 wv = *reinterpret_cast<const float4*>(wr + 4 * k4);
#pragma unroll
        for (int b = 0; b < 8; ++b) {
            const float4 xv = *reinterpret_cast<const float4*>(xb + b * F + 4 * k4);
            y[b] = fmaf(xv.x, wv.x, y[b]);
            y[b] = fmaf(xv.y, wv.y, y[b]);
            y[b] = fmaf(xv.z, wv.z, y[b]);
            y[b] = fmaf(xv.w, wv.w, y[b]);
        }
    }

    union { unsigned short us[8]; uint4 v; } pk;
#pragma unroll
    for (int b = 0; b < 8; ++b) pk.us[b] = f2bf(y[b]);
    yfrag[(js * 4 + t) * 64 + ld] = pk.v;
}

// ---------------- main kernel ----------------
__global__ __launch_bounds__(512, 4)   // cap VGPR at 128 -> 2 blocks/CU, 16 waves/CU
void gcn_main(const float* __restrict__ se, const float* __restrict__ te,
              const uint4* __restrict__ yfrag, const float* __restrict__ bias,
              float* __restrict__ out)
{
    const int tid  = threadIdx.x;
    const int lane = tid & 63;
    const int wave = tid >> 6;
    const int g    = lane >> 4;     // k-group 0..3
    const int il   = lane & 15;     // A-row within tile / D-feature within tile
    const int rt   = wave & 1;      // row-tile within block (2)
    const int js   = wave >> 1;     // j-split 0..3
    const int rowbase = (blockIdx.x << 5) + (rt << 4);
    const int row  = rowbase + il;

    float u[RANK];
#pragma unroll
    for (int r = 0; r < RANK; ++r) u[r] = se[row * RANK + r];

    f32x4 acc0 = {0.f,0.f,0.f,0.f}, acc1 = {0.f,0.f,0.f,0.f};
    f32x4 acc2 = {0.f,0.f,0.f,0.f}, acc3 = {0.f,0.f,0.f,0.f};
    float lsum = 0.f;

    const int j0 = js * (N / 4);
    for (int s = 0; s < (N / 4) / 32; ++s) {   // 128 K-steps of 32
        const int jb = j0 + (s << 5);
        const int jl = jb + (g << 3);          // this lane's 8-j base

        float pv[8];
#pragma unroll
        for (int h = 0; h < 2; ++h) {
            float tv[RANK][4];
#pragma unroll
            for (int r = 0; r < RANK; ++r) {
                const float4 t4 = *reinterpret_cast<const float4*>(te + r * N + jl + 4 * h);
                tv[r][0] = t4.x; tv[r][1] = t4.y; tv[r][2] = t4.z; tv[r][3] = t4.w;
            }
#pragma unroll
            for (int q = 0; q < 4; ++q) {
                const float d0 = fmaf(u[0], tv[0][q], u[1] * tv[1][q]);
                const float d1 = fmaf(u[2], tv[2][q], u[3] * tv[3][q]);
                const float d2 = fmaf(u[4], tv[4][q], u[5] * tv[5][q]);
                const float d3 = fmaf(u[6], tv[6][q], u[7] * tv[7][q]);
                const float d4 = fmaf(u[8], tv[8][q], u[9] * tv[9][q]);
                float sc = (d0 + d1) + (d2 + d3) + d4;
                sc = fmaxf(sc, 0.f);
                const float p = __expf(sc);
                lsum += p;
                pv[4 * h + q] = p;
            }
        }

        bf16x8 af;
#pragma unroll
        for (int b = 0; b < 8; ++b) af[b] = (short)f2bf(pv[b]);

        const uint4* yb = yfrag + (size_t)(jb >> 5) * 256 + lane;
        const uint4 b0 = yb[0];
        const uint4 b1 = yb[64];
        const uint4 b2 = yb[128];
        const uint4 b3 = yb[192];
        acc0 = __builtin_amdgcn_mfma_f32_16x16x32_bf16(af, __builtin_bit_cast(bf16x8, b0), acc0, 0, 0, 0);
        acc1 = __builtin_amdgcn_mfma_f32_16x16x32_bf16(af, __builtin_bit_cast(bf16x8, b1), acc1, 0, 0, 0);
        acc2 = __builtin_amdgcn_mfma_f32_16x16x32_bf16(af, __builtin_bit_cast(bf16x8, b2), acc2, 0, 0, 0);
        acc3 = __builtin_amdgcn_mfma_f32_16x16x32_bf16(af, __builtin_bit_cast(bf16x8, b3), acc3, 0, 0, 0);
    }

    // full per-row lsum for this j-split: combine the 4 k-groups
    lsum += __shfl_xor(lsum, 16);
    lsum += __shfl_xor(lsum, 32);

    // ---- block combine across the 4 j-splits ----
    __shared__ float s_acc[8][1024];   // [wave][row16*64 + feat]
    __shared__ float s_l[8][16];

#pragma unroll
    for (int r_ = 0; r_ < 4; ++r_) {
        const int rowi = 4 * g + r_;   // D row = (lane>>4)*4 + reg  (m89 layout)
        s_acc[wave][rowi * 64 +  0 + il] = acc0[r_];
        s_acc[wave][rowi * 64 + 16 + il] = acc1[r_];
        s_acc[wave][rowi * 64 + 32 + il] = acc2[r_];
        s_acc[wave][rowi * 64 + 48 + il] = acc3[r_];
    }
    if (g == 0) s_l[wave][il] = lsum;
    __syncthreads();

    // 512 threads x 4 floats = 2048 outputs (32 rows x 64 feats)
    const int e     = tid << 2;
    const int rt2   = e >> 10;
    const int idx   = e & 1023;
    const int row16 = idx >> 6;
    const int feat  = idx & 63;

    f32x4 v = {0.f,0.f,0.f,0.f};
    float ls = 0.f;
#pragma unroll
    for (int sp = 0; sp < 4; ++sp) {
        const int w = sp * 2 + rt2;    // wave = js*2 + rt
        const f32x4 a = *reinterpret_cast<const f32x4*>(&s_acc[w][idx]);
        v = v + a;
        ls += s_l[w][row16];
    }
    const float inv = 1.f / ls;
    const float4 bv = *reinterpret_cast<const float4*>(bias + feat);
    float4 o;
    o.x = v[0] * inv + bv.x;
    o.y = v[1] * inv + bv.y;
    o.z = v[2] * inv + bv.z;
    o.w = v[3] * inv + bv.w;
    *reinterpret_cast<float4*>(out + (size_t)((blockIdx.x << 5) + (rt2 << 4) + row16) * F + feat) = o;
}

extern "C" void kernel_launch(void* const* d_in, const int* in_sizes, int n_in,
                              void* d_out, int out_size, void* d_ws, size_t ws_size,
                              hipStream_t stream) {
    const float* x  = (const float*)d_in[0];
    const float* se = (const float*)d_in[1];
    const float* te = (const float*)d_in[2];
    const float* W  = (const float*)d_in[3];
    const float* b  = (const float*)d_in[4];
    float* out = (float*)d_out;

    uint4* yfrag = (uint4*)d_ws;   // 512*4*64*16 B = 2 MiB

    prep_y<<<N / 32, 256, 0, stream>>>(x, W, yfrag);
    gcn_main<<<N / 32, 512, 0, stream>>>(se, te, yfrag, b, out);
}

// Round 6
// 167.750 us; speedup vs baseline: 12.9467x; 2.5893x over previous
//
#include <hip/hip_runtime.h>
#include <hip/hip_bf16.h>

// LearnedGCN: out = softmax(relu(se @ te), axis=1) @ x @ W.T + b
// N=16384, RANK=10, F=64, fp32 in/out.
//
// Round-5: identical math to Round-4 (both matmuls on MFMA, 3-band hi/lo score
// compensation), but total d_ws footprint cut 3MiB -> 1.625MiB by splitting the
// j-range into two halves processed by two sequential gcn launches that share
// one half-sized fragment workspace. Phase A writes raw fp32 partials into
// d_out (write-only); phase B adds its partials in-place, normalizes, biases.
// Rationale: R4 (3MiB ws) passed first validation but later launches were
// consistently wrong -> OOB ws writes corrupting an adjacent pristine buffer;
// R3 (2MiB ws) passed post-timing cleanly, so stay strictly under 2MiB.

constexpr int N    = 16384;
constexpr int RANK = 10;
constexpr int F    = 64;
constexpr int NH   = N / 2;          // j per phase

typedef float f32x4 __attribute__((ext_vector_type(4)));
typedef short bf16x8 __attribute__((ext_vector_type(8)));

static __device__ __forceinline__ unsigned short f2bf_rne(float f) {
    union { float f; unsigned int u; } a; a.f = f;
    unsigned int u = a.u;
    u += 0x7FFFu + ((u >> 16) & 1u);   // round-to-nearest-even
    return (unsigned short)(u >> 16);
}
static __device__ __forceinline__ float bf2f(unsigned short h) {
    union { unsigned int u; float f; } a; a.u = ((unsigned int)h) << 16;
    return a.f;
}

// -------- prep_te: A-frags of te^T for a j-half, K-banded (hi|hi|lo) ---------
// tefrag[lt*64 + lane] slot b: k=8g+b; k<10: te_hi[r=k], k<20: te_hi[k-10],
// k<30: te_lo[k-20], else 0.  Value at te[r][(jt0+lt)*16 + il].
__global__ __launch_bounds__(256)
void prep_te(const float* __restrict__ te, uint4* __restrict__ tefrag, int jt0) {
    const int tid  = threadIdx.x;
    const int lt   = blockIdx.x * 4 + (tid >> 6);   // local tile 0..511
    const int jt   = jt0 + lt;
    const int lane = tid & 63;
    const int g = lane >> 4, il = lane & 15;
    union { unsigned short us[8]; uint4 v; } pk;
#pragma unroll
    for (int b = 0; b < 8; ++b) {
        const int k = 8 * g + b;
        unsigned short o = 0;
        if (k < 30) {
            const int band = (k < 10) ? 0 : (k < 20 ? 1 : 2);
            const int r = k - band * 10;
            const float v = te[r * N + jt * 16 + il];
            const unsigned short h = f2bf_rne(v);
            o = (band == 2) ? f2bf_rne(v - bf2f(h)) : h;
        }
        pk.us[b] = o;
    }
    tefrag[lt * 64 + lane] = pk.v;
}

// -------- prep_y: Y = X @ W.T for a j-half, bf16, PV B-frag order ------------
// yfrag[(jl*4 + t)*64 + lane] slot b = Y[(js0+jl)*32 + 16*(b>>2)+4*g+(b&3)][t*16+il]
__global__ __launch_bounds__(256)
void prep_y(const float* __restrict__ x, const float* __restrict__ W,
            uint4* __restrict__ yfrag, int js0) {
    __shared__ float xs[32][68];   // stride 68: breaks 4-row bank congruence
    const int jl  = blockIdx.x;            // local js 0..255
    const int js  = js0 + jl;
    const int tid = threadIdx.x;
#pragma unroll
    for (int i = 0; i < 2; ++i) {
        const int fi = tid * 2 + i;        // 0..511 float4 slots
        const int r = fi >> 4, c4 = fi & 15;
        const float4 v = *reinterpret_cast<const float4*>(x + (size_t)(js * 32 + r) * F + c4 * 4);
        *reinterpret_cast<float4*>(&xs[r][c4 * 4]) = v;
    }
    __syncthreads();
    const int t = tid >> 6, lane = tid & 63;
    const int g = lane >> 4, il = lane & 15;
    const int f = t * 16 + il;
    float y[8];
#pragma unroll
    for (int b = 0; b < 8; ++b) y[b] = 0.f;
    const float* wr = W + f * F;
#pragma unroll
    for (int k4 = 0; k4 < F / 4; ++k4) {
        const float4 wv = *reinterpret_cast<const float4*>(wr + 4 * k4);
#pragma unroll
        for (int b = 0; b < 8; ++b) {
            const int row = 16 * (b >> 2) + 4 * g + (b & 3);
            const float4 xv = *reinterpret_cast<const float4*>(&xs[row][4 * k4]);
            y[b] = fmaf(xv.x, wv.x, y[b]);
            y[b] = fmaf(xv.y, wv.y, y[b]);
            y[b] = fmaf(xv.z, wv.z, y[b]);
            y[b] = fmaf(xv.w, wv.w, y[b]);
        }
    }
    union { unsigned short us[8]; uint4 v; } pk;
#pragma unroll
    for (int b = 0; b < 8; ++b) pk.us[b] = f2bf_rne(y[b]);
    yfrag[(jl * 4 + t) * 64 + lane] = pk.v;
}

// -------- main kernel (one j-half) ------------------------------------------
// phase 0: out <- raw fp32 partial agg; lsum_self[row] <- partial lsum.
// phase 1: out <- (out + partial)/ (lsum_other+partial_lsum) + bias.
__global__ __launch_bounds__(512, 4)
void gcn_main(const float* __restrict__ se, const uint4* __restrict__ tefrag,
              const uint4* __restrict__ yfrag, const float* __restrict__ bias,
              float* __restrict__ out, float* __restrict__ lsum_self,
              const float* __restrict__ lsum_other, int phase) {
    const int tid  = threadIdx.x;
    const int lane = tid & 63;
    const int wave = tid >> 6;           // j-split 0..7 within this half
    const int g = lane >> 4, il = lane & 15;
    const int rowbase = blockIdx.x << 5; // 32 rows per block

    // se^T B-frags (hi|lo|hi banding — pairs with te's hi|hi|lo), per row-tile
    bf16x8 sef[2];
#pragma unroll
    for (int rt = 0; rt < 2; ++rt) {
        union { short s8[8]; bf16x8 v; } pk;
        const int row = rowbase + rt * 16 + il;
#pragma unroll
        for (int b = 0; b < 8; ++b) {
            const int k = 8 * g + b;
            unsigned short o = 0;
            if (k < 30) {
                const int band = (k < 10) ? 0 : (k < 20 ? 1 : 2);
                const int r = k - band * 10;
                const float v = se[row * RANK + r];
                const unsigned short h = f2bf_rne(v);
                o = (band == 1) ? f2bf_rne(v - bf2f(h)) : h;
            }
            pk.s8[b] = (short)o;
        }
        sef[rt] = pk.v;
    }

    f32x4 acc[2][4];
#pragma unroll
    for (int rt = 0; rt < 2; ++rt)
#pragma unroll
        for (int ft = 0; ft < 4; ++ft) acc[rt][ft] = f32x4{0.f, 0.f, 0.f, 0.f};
    float lsum0 = 0.f, lsum1 = 0.f;

    // this wave's j-chunk within the half: 1024 j = 32 K-steps of 32 j
    const uint4* tb = tefrag + (size_t)wave * 64 * 64 + lane;   // (1024/16)=64 tiles
    const uint4* yb = yfrag + (size_t)wave * 32 * 256 + lane;   // (1024/32)=32 js

    for (int s = 0; s < 32; ++s) {
        const uint4 ta0 = tb[0];
        const uint4 ta1 = tb[64];
        const f32x4 z = {0.f, 0.f, 0.f, 0.f};
        f32x4 sc00 = __builtin_amdgcn_mfma_f32_16x16x32_bf16(__builtin_bit_cast(bf16x8, ta0), sef[0], z, 0, 0, 0);
        f32x4 sc01 = __builtin_amdgcn_mfma_f32_16x16x32_bf16(__builtin_bit_cast(bf16x8, ta1), sef[0], z, 0, 0, 0);
        f32x4 sc10 = __builtin_amdgcn_mfma_f32_16x16x32_bf16(__builtin_bit_cast(bf16x8, ta0), sef[1], z, 0, 0, 0);
        f32x4 sc11 = __builtin_amdgcn_mfma_f32_16x16x32_bf16(__builtin_bit_cast(bf16x8, ta1), sef[1], z, 0, 0, 0);

        union { short s8[8]; bf16x8 v; } af0, af1;
#pragma unroll
        for (int q = 0; q < 4; ++q) {
            const float p00 = __expf(fmaxf(sc00[q], 0.f));
            const float p01 = __expf(fmaxf(sc01[q], 0.f));
            const float p10 = __expf(fmaxf(sc10[q], 0.f));
            const float p11 = __expf(fmaxf(sc11[q], 0.f));
            lsum0 += p00 + p01;
            lsum1 += p10 + p11;
            af0.s8[q]     = (short)__builtin_bit_cast(unsigned short, __float2bfloat16(p00));
            af0.s8[4 + q] = (short)__builtin_bit_cast(unsigned short, __float2bfloat16(p01));
            af1.s8[q]     = (short)__builtin_bit_cast(unsigned short, __float2bfloat16(p10));
            af1.s8[4 + q] = (short)__builtin_bit_cast(unsigned short, __float2bfloat16(p11));
        }

        const uint4 y0 = yb[0];
        const uint4 y1 = yb[64];
        acc[0][0] = __builtin_amdgcn_mfma_f32_16x16x32_bf16(af0.v, __builtin_bit_cast(bf16x8, y0), acc[0][0], 0, 0, 0);
        acc[1][0] = __builtin_amdgcn_mfma_f32_16x16x32_bf16(af1.v, __builtin_bit_cast(bf16x8, y0), acc[1][0], 0, 0, 0);
        acc[0][1] = __builtin_amdgcn_mfma_f32_16x16x32_bf16(af0.v, __builtin_bit_cast(bf16x8, y1), acc[0][1], 0, 0, 0);
        acc[1][1] = __builtin_amdgcn_mfma_f32_16x16x32_bf16(af1.v, __builtin_bit_cast(bf16x8, y1), acc[1][1], 0, 0, 0);
        const uint4 y2 = yb[128];
        const uint4 y3 = yb[192];
        acc[0][2] = __builtin_amdgcn_mfma_f32_16x16x32_bf16(af0.v, __builtin_bit_cast(bf16x8, y2), acc[0][2], 0, 0, 0);
        acc[1][2] = __builtin_amdgcn_mfma_f32_16x16x32_bf16(af1.v, __builtin_bit_cast(bf16x8, y2), acc[1][2], 0, 0, 0);
        acc[0][3] = __builtin_amdgcn_mfma_f32_16x16x32_bf16(af0.v, __builtin_bit_cast(bf16x8, y3), acc[0][3], 0, 0, 0);
        acc[1][3] = __builtin_amdgcn_mfma_f32_16x16x32_bf16(af1.v, __builtin_bit_cast(bf16x8, y3), acc[1][3], 0, 0, 0);

        tb += 128;
        yb += 256;
    }

    // per-row lsum within this wave's chunk: combine the 4 k-groups
    lsum0 += __shfl_xor(lsum0, 16); lsum0 += __shfl_xor(lsum0, 32);
    lsum1 += __shfl_xor(lsum1, 16); lsum1 += __shfl_xor(lsum1, 32);

    // ---- combine 8 wave-chunks: 2-phase into 4 LDS buffers (32KB) ----
    __shared__ float s_acc[4][2048];
    __shared__ float s_l[8][32];

    if (g == 0) { s_l[wave][il] = lsum0; s_l[wave][16 + il] = lsum1; }

    if (wave < 4) {
#pragma unroll
        for (int rt = 0; rt < 2; ++rt)
#pragma unroll
            for (int ft = 0; ft < 4; ++ft)
#pragma unroll
                for (int q = 0; q < 4; ++q)
                    s_acc[wave][(rt * 16 + 4 * g + q) * 64 + ft * 16 + il] = acc[rt][ft][q];
    }
    __syncthreads();
    if (wave >= 4) {
#pragma unroll
        for (int rt = 0; rt < 2; ++rt)
#pragma unroll
            for (int ft = 0; ft < 4; ++ft)
#pragma unroll
                for (int q = 0; q < 4; ++q) {
                    const int a = (rt * 16 + 4 * g + q) * 64 + ft * 16 + il;
                    s_acc[wave - 4][a] += acc[rt][ft][q];
                }
    }
    __syncthreads();

    // 512 threads x 4 floats = 2048 outputs (32 rows x 64 feats)
    const int idx  = tid << 2;
    const int row  = idx >> 6;
    const int feat = idx & 63;
    f32x4 v = {0.f, 0.f, 0.f, 0.f};
#pragma unroll
    for (int w = 0; w < 4; ++w) v = v + *reinterpret_cast<const f32x4*>(&s_acc[w][idx]);
    float ls = 0.f;
#pragma unroll
    for (int w = 0; w < 8; ++w) ls += s_l[w][row];

    const int orow = rowbase + row;
    float* op = out + (size_t)orow * F + feat;

    if (phase == 0) {
        if (feat == 0) lsum_self[orow] = ls;
        float4 o; o.x = v[0]; o.y = v[1]; o.z = v[2]; o.w = v[3];
        *reinterpret_cast<float4*>(op) = o;
    } else {
        const float4 prev = *reinterpret_cast<const float4*>(op);
        const float lst = ls + lsum_other[orow];
        const float inv = 1.f / lst;
        const float4 bv = *reinterpret_cast<const float4*>(bias + feat);
        float4 o;
        o.x = (v[0] + prev.x) * inv + bv.x;
        o.y = (v[1] + prev.y) * inv + bv.y;
        o.z = (v[2] + prev.z) * inv + bv.z;
        o.w = (v[3] + prev.w) * inv + bv.w;
        *reinterpret_cast<float4*>(op) = o;
    }
}

extern "C" void kernel_launch(void* const* d_in, const int* in_sizes, int n_in,
                              void* d_out, int out_size, void* d_ws, size_t ws_size,
                              hipStream_t stream) {
    const float* x  = (const float*)d_in[0];
    const float* se = (const float*)d_in[1];
    const float* te = (const float*)d_in[2];
    const float* W  = (const float*)d_in[3];
    const float* b  = (const float*)d_in[4];
    float* out = (float*)d_out;

    // ws layout (1.625 MiB total; R3 proved >=2MiB is safe):
    //   [0, 512K)        tefrag half  (512 tiles x 64 x 16B)
    //   [512K, 1.5M)     yfrag half   (256 js x 4 x 64 x 16B)
    //   [1.5M, 1.5M+64K) lsumA        [.., +128K) lsumB
    uint4* tefrag = (uint4*)d_ws;
    uint4* yfrag  = (uint4*)((char*)d_ws + (512u << 10));
    float* lsumA  = (float*)((char*)d_ws + (1536u << 10));
    float* lsumB  = lsumA + N;

    // phase A: j in [0, 8192)
    prep_te<<<NH / 16 / 4, 256, 0, stream>>>(te, tefrag, 0);
    prep_y <<<NH / 32,     256, 0, stream>>>(x, W, yfrag, 0);
    gcn_main<<<N / 32, 512, 0, stream>>>(se, tefrag, yfrag, b, out, lsumA, lsumB, 0);

    // phase B: j in [8192, 16384)
    prep_te<<<NH / 16 / 4, 256, 0, stream>>>(te, tefrag, NH / 16);
    prep_y <<<NH / 32,     256, 0, stream>>>(x, W, yfrag, NH / 32);
    gcn_main<<<N / 32, 512, 0, stream>>>(se, tefrag, yfrag, b, out, lsumB, lsumA, 1);
}